// Round 11
// baseline (209.474 us; speedup 1.0000x reference)
//
#include <hip/hip_runtime.h>

#define T_TOK 4096
#define D_DIM 512
#define F_DIM 1024
#define E_NUM 8
#define CAP   2048
#define BM    128
#define BN    64
#define BK    64
#define MT    (CAP/BM)      // 16
#define NT_GU (F_DIM/BN)    // 16
#define NT_DN (D_DIM/BN)    // 8
#define RB_TOK 32
#define CSTRIDE 32

#define GU_HALF (BM*BK*2 + 2*BN*BK*2)   // 32768 bytes per buffer
#define DN_HALF (BM*BK*2 + BN*BK*2)     // 24576 bytes per buffer

typedef __bf16 bf16x8 __attribute__((ext_vector_type(8)));
typedef float  f32x4  __attribute__((ext_vector_type(4)));

__device__ __forceinline__ unsigned short f2bf(float f){
  unsigned int u = __builtin_bit_cast(unsigned int, f);
  u += 0x7FFFu + ((u >> 16) & 1u);
  return (unsigned short)(u >> 16);
}
__device__ __forceinline__ unsigned pk2(float a, float b){
  return (unsigned)f2bf(a) | ((unsigned)f2bf(b)<<16);
}
__device__ __forceinline__ void gload16(const void* g, void* l){
  __builtin_amdgcn_global_load_lds(
      (const __attribute__((address_space(1))) unsigned int*)g,
      (__attribute__((address_space(3))) unsigned int*)l, 16, 0, 0);
}

// ============ router: logits + softmax + top2 + aux + bf16 scatter into Xg ============
__global__ __launch_bounds__(256) void router_kernel(
    const float* __restrict__ x, const float* __restrict__ rw,
    unsigned short* __restrict__ Xg,
    int* __restrict__ cnt, int* __restrict__ slot_token, float* __restrict__ slot_w,
    float* __restrict__ Psum, float* __restrict__ zsum)
{
  __shared__ float rws[E_NUM*D_DIM];
  __shared__ float lp[RB_TOK][E_NUM];
  __shared__ float lw1[RB_TOK], lw2[RB_TOK], llse[RB_TOK];
  __shared__ int   li1[RB_TOK], li2[RB_TOK], lsl1[RB_TOK], lsl2[RB_TOK];
  int b = blockIdx.x, tid = threadIdx.x;
  int wid = tid>>6, lane = tid&63;
  for (int i = tid; i < E_NUM*D_DIM; i += 256) rws[i] = rw[i];
  __syncthreads();

  uint4 pk[8];
  #pragma unroll
  for (int i=0;i<8;i++){
    int widx = wid*8 + i;
    int t = b*RB_TOK + widx;
    const float* xr = x + (size_t)t*D_DIM + lane*8;
    float4 xa = *(const float4*)xr;
    float4 xc = *(const float4*)(xr+4);
    pk[i].x = pk2(xa.x, xa.y);
    pk[i].y = pk2(xa.z, xa.w);
    pk[i].z = pk2(xc.x, xc.y);
    pk[i].w = pk2(xc.z, xc.w);

    float logit[E_NUM];
    #pragma unroll
    for (int e=0;e<E_NUM;e++){
      const float* wr = rws + e*D_DIM + lane*8;
      float4 wa = *(const float4*)wr;
      float4 wb = *(const float4*)(wr+4);
      float s = xa.x*wa.x + xa.y*wa.y + xa.z*wa.z + xa.w*wa.w
              + xc.x*wb.x + xc.y*wb.y + xc.z*wb.z + xc.w*wb.w;
      #pragma unroll
      for (int m=1;m<64;m<<=1) s += __shfl_xor(s, m);
      logit[e] = s;
    }
    float mx = logit[0];
    #pragma unroll
    for (int e=1;e<E_NUM;e++) mx = fmaxf(mx, logit[e]);
    float p[E_NUM]; float s = 0.f;
    #pragma unroll
    for (int e=0;e<E_NUM;e++){ p[e] = __expf(logit[e]-mx); s += p[e]; }
    float inv = 1.f/s;
    #pragma unroll
    for (int e=0;e<E_NUM;e++) p[e] *= inv;
    float lse = mx + __logf(s);
    int i1 = 0;
    #pragma unroll
    for (int e=1;e<E_NUM;e++) if (logit[e] > logit[i1]) i1 = e;
    int i2 = (i1==0) ? 1 : 0;
    #pragma unroll
    for (int e=0;e<E_NUM;e++) if (e != i1 && logit[e] > logit[i2]) i2 = e;
    if (lane == 0){
      float v1 = p[i1], v2 = p[i2];
      float invw = 1.f/(v1+v2);
      li1[widx] = i1; li2[widx] = i2;
      lw1[widx] = v1*invw; lw2[widx] = v2*invw;
      llse[widx] = lse;
      #pragma unroll
      for (int e=0;e<E_NUM;e++) lp[widx][e] = p[e];
    }
  }
  __syncthreads();

  if (tid < E_NUM){
    int e = tid, c = 0;
    #pragma unroll 4
    for (int j=0;j<RB_TOK;j++) c += (li1[j]==e) + (li2[j]==e);
    int idx = atomicAdd(&cnt[e*CSTRIDE], c);
    int tbase = b*RB_TOK;
    for (int j=0;j<RB_TOK;j++){
      if (li1[j]==e){ slot_token[e*CAP+idx] = tbase+j; slot_w[e*CAP+idx] = lw1[j]; lsl1[j] = e*CAP+idx; idx++; }
      if (li2[j]==e){ slot_token[e*CAP+idx] = tbase+j; slot_w[e*CAP+idx] = lw2[j]; lsl2[j] = e*CAP+idx; idx++; }
    }
    float ps = 0.f;
    #pragma unroll 4
    for (int j=0;j<RB_TOK;j++) ps += lp[j][e];
    atomicAdd(&Psum[e*CSTRIDE], ps);
  } else if (tid == 64){
    float zs = 0.f;
    #pragma unroll 4
    for (int j=0;j<RB_TOK;j++){ float l = llse[j]; zs += l*l; }
    atomicAdd(zsum, zs);
  }
  __syncthreads();

  #pragma unroll
  for (int i=0;i<8;i++){
    int widx = wid*8 + i;
    *(uint4*)((char*)Xg + (size_t)lsl1[widx]*(D_DIM*2) + lane*16) = pk[i];
    *(uint4*)((char*)Xg + (size_t)lsl2[widx]*(D_DIM*2) + lane*16) = pk[i];
  }
}

// ============ transpose: [E][R][C] fp32 -> [E][C][R] bf16, b32-pack + XOR, conflict-free ============
__global__ __launch_bounds__(256) void transpose_kernel(
    const float* __restrict__ gw, const float* __restrict__ uw, const float* __restrict__ dw,
    unsigned short* __restrict__ gwt, unsigned short* __restrict__ uwt, unsigned short* __restrict__ dwt)
{
  __shared__ unsigned tw[64*32];     // 8 KB: 64 cols x 32 k-pair words
  int tb = blockIdx.x;
  int seg = tb >> 10;                // 0:gw 1:uw 2:dw
  int r1023 = tb & 1023;
  int e = r1023 >> 7;
  int rr = r1023 & 127;
  const float* in; unsigned short* outp; int R, C, nbx;
  if (seg == 0){ in = gw; outp = gwt; R = D_DIM; C = F_DIM; nbx = F_DIM/64; }
  else if (seg == 1){ in = uw; outp = uwt; R = D_DIM; C = F_DIM; nbx = F_DIM/64; }
  else { in = dw; outp = dwt; R = F_DIM; C = D_DIM; nbx = D_DIM/64; }
  int c0 = (rr % nbx)*64, r0 = (rr / nbx)*64;
  const float* src = in + (size_t)e*R*C;
  unsigned short* dst = outp + (size_t)e*R*C;
  int tid = threadIdx.x;

  // write phase: thread loads rows 2*d2, 2*d2+1, cols fcq*8..+7; packs k-pairs -> 8 b32 writes
  int d2 = tid>>3, fcq = tid&7;
  const float* p0 = src + (size_t)(r0 + 2*d2)*C + c0 + fcq*8;
  float4 a0 = *(const float4*)p0;
  float4 a1 = *(const float4*)(p0+4);
  float4 b0 = *(const float4*)(p0+C);
  float4 b1 = *(const float4*)(p0+C+4);
  float al[8] = {a0.x,a0.y,a0.z,a0.w,a1.x,a1.y,a1.z,a1.w};
  float bl[8] = {b0.x,b0.y,b0.z,b0.w,b1.x,b1.y,b1.z,b1.w};
  unsigned xb = ((unsigned)fcq)<<2;       // = (c>>3)<<2 for c = fcq*8+j
  #pragma unroll
  for (int j=0;j<8;j++){
    int c = fcq*8 + j;
    tw[c*32 + (d2 ^ xb)] = pk2(al[j], bl[j]);
  }
  __syncthreads();

  // read phase: thread (c, q) reads 8 words (2 x b128, same XOR) -> 2 coalesced uint4 stores
  int c = tid>>2, q = tid&3;
  unsigned xc = ((unsigned)(c>>3))<<2;
  uint4 v0 = *(const uint4*)&tw[c*32 + ((unsigned)(q*8+0) ^ xc)];
  uint4 v1 = *(const uint4*)&tw[c*32 + ((unsigned)(q*8+4) ^ xc)];
  unsigned short* dp = dst + (size_t)(c0+c)*R + r0 + q*16;
  *(uint4*)dp = v0;
  *(uint4*)(dp+8) = v1;
}

// ---------------- gate+up GEMM: 2-deep pipeline, counted vmcnt ----------------
__global__ __launch_bounds__(256) void gemm_gateup(
    const unsigned short* __restrict__ Xg, const unsigned short* __restrict__ gwt,
    const unsigned short* __restrict__ uwt,
    const int* __restrict__ cnt,
    const float* __restrict__ slot_w, unsigned short* __restrict__ H)
{
  int fid = blockIdx.x;
  int nid = (fid & 7)*(E_NUM*MT*NT_GU/8) + (fid >> 3);
  int e  = nid >> 8;
  int r  = nid & 255;
  int n0 = (r >> 4) * BN;
  int mt = r & 15;
  int c = cnt[e*CSTRIDE];
  int row0 = mt*BM;
  if (row0 >= c) return;
  int rem = c - row0;
  int offe = 0;
  #pragma unroll
  for (int i=0;i<E_NUM;i++) offe += (i < e) ? cnt[i*CSTRIDE] : 0;
  int tid = threadIdx.x, wid = tid>>6, lane = tid&63;
  __shared__ __align__(16) char arena[2*GU_HALF];

  int sub = lane>>3;
  int skb = ((lane&7)<<4) ^ (sub<<4);
  const char* asrc[4];
  #pragma unroll
  for (int i=0;i<4;i++){
    int rr = (wid*4+i)*8 + sub;
    asrc[i] = (const char*)Xg + ((size_t)e*CAP + row0 + rr)*(D_DIM*2) + skb;
  }
  const char* bgsrc[2]; const char* busrc[2];
  #pragma unroll
  for (int i=0;i<2;i++){
    int rr = (wid*2+i)*8 + sub;
    size_t rowb = ((size_t)e*F_DIM + n0 + rr) * (D_DIM*2);
    bgsrc[i] = (const char*)gwt + rowb + skb;
    busrc[i] = (const char*)uwt + rowb + skb;
  }

  f32x4 accg[4][2] = {};
  f32x4 accu[4][2] = {};
  int wm = wid>>1, wn = wid&1;

  auto STAGE = [&](int buf, int kt){           // 8 gload_lds per thread
    size_t ko = (size_t)kt*BK*2;
    char* base = arena + buf*GU_HALF;
    #pragma unroll
    for (int i=0;i<4;i++)
      gload16(asrc[i]+ko, base + (wid*4+i)*1024);
    #pragma unroll
    for (int i=0;i<2;i++){
      gload16(bgsrc[i]+ko, base + BM*BK*2 + (wid*2+i)*1024);
      gload16(busrc[i]+ko, base + BM*BK*2 + BN*BK*2 + (wid*2+i)*1024);
    }
  };
  auto COMPUTE = [&](int buf){
    const char* base = arena + buf*GU_HALF;
    const char* Bg = base + BM*BK*2;
    const char* Bu = base + BM*BK*2 + BN*BK*2;
    #pragma unroll
    for (int s=0;s<2;s++){
      int kc = s*4 + (lane>>4);
      bf16x8 a[4], bg[2], bu[2];
      #pragma unroll
      for (int m=0;m<4;m++){
        int ar = wm*64 + m*16 + (lane&15);
        a[m] = *(const bf16x8*)(base + ar*128 + ((kc<<4) ^ ((ar&7)<<4)));
      }
      #pragma unroll
      for (int n=0;n<2;n++){
        int br = wn*32 + n*16 + (lane&15);
        int bo = br*128 + ((kc<<4) ^ ((br&7)<<4));
        bg[n] = *(const bf16x8*)(Bg + bo);
        bu[n] = *(const bf16x8*)(Bu + bo);
      }
      #pragma unroll
      for (int m=0;m<4;m++){
        #pragma unroll
        for (int n=0;n<2;n++){
          accg[m][n] = __builtin_amdgcn_mfma_f32_16x16x32_bf16(a[m], bg[n], accg[m][n], 0,0,0);
          accu[m][n] = __builtin_amdgcn_mfma_f32_16x16x32_bf16(a[m], bu[n], accu[m][n], 0,0,0);
        }
      }
    }
  };

  STAGE(0, 0);
  STAGE(1, 1);
  #pragma unroll 1
  for (int t=0; t<D_DIM/BK-1; ++t){
    asm volatile("s_waitcnt vmcnt(8)" ::: "memory");   // tile t done; t+1 in flight
    __builtin_amdgcn_s_barrier();
    __builtin_amdgcn_sched_barrier(0);
    COMPUTE(t & 1);
    __builtin_amdgcn_s_barrier();                      // all waves done reading buf
    __builtin_amdgcn_sched_barrier(0);
    if (t+2 < D_DIM/BK) STAGE(t & 1, t+2);
  }
  asm volatile("s_waitcnt vmcnt(0)" ::: "memory");
  __builtin_amdgcn_s_barrier();
  __builtin_amdgcn_sched_barrier(0);
  COMPUTE((D_DIM/BK-1) & 1);

  #pragma unroll
  for (int m=0;m<4;m++){
    #pragma unroll
    for (int j=0;j<4;j++){
      int row = wm*64 + m*16 + ((lane>>4)<<2) + j;
      if (row < rem){
        float wgt = slot_w[e*CAP + row0 + row];
        size_t hb = (size_t)(offe + row0 + row)*F_DIM;
        #pragma unroll
        for (int n=0;n<2;n++){
          int col = n0 + wn*32 + n*16 + (lane&15);
          float g = accg[m][n][j];
          float u = accu[m][n][j];
          float h = g * (1.f/(1.f+__expf(-g))) * u * wgt;
          H[hb + col] = f2bf(h);
        }
      }
    }
  }
}

// ---------------- down GEMM: 2-deep pipeline, counted vmcnt, atomic scatter ----------------
__global__ __launch_bounds__(256) void gemm_down(
    const unsigned short* __restrict__ H, const unsigned short* __restrict__ dwt,
    const int* __restrict__ cnt,
    const int* __restrict__ slot_token, float* __restrict__ out,
    const float* __restrict__ Psum, const float* __restrict__ zsum)
{
  int fid = blockIdx.x;
  int tid = threadIdx.x;
  if (fid == 0 && tid == 0){
    float lb = 0.f;
    #pragma unroll
    for (int e=0;e<E_NUM;e++){
      float f = (float)cnt[e*CSTRIDE] / (float)(T_TOK*2);
      float P = Psum[e*CSTRIDE] / (float)T_TOK;
      lb += f*P;
    }
    float z = zsum[0] / (float)T_TOK;
    out[(size_t)T_TOK*D_DIM] = 0.01f * ((float)E_NUM * lb) + 0.001f * z;
  }
  int nid = (fid & 7)*(E_NUM*MT*NT_DN/8) + (fid >> 3);
  int e  = nid >> 7;
  int r  = nid & 127;
  int n0 = (r >> 4) * BN;
  int mt = r & 15;
  int c = cnt[e*CSTRIDE];
  int row0 = mt*BM;
  if (row0 >= c) return;
  int rem = c - row0;
  int offe = 0;
  #pragma unroll
  for (int i=0;i<E_NUM;i++) offe += (i < e) ? cnt[i*CSTRIDE] : 0;
  int wid = tid>>6, lane = tid&63;
  __shared__ __align__(16) char arena[2*DN_HALF];
  int sub = lane>>3;
  int skb = ((lane&7)<<4) ^ (sub<<4);
  const char* asrc[4];
  #pragma unroll
  for (int i=0;i<4;i++){
    int rr = (wid*4+i)*8 + sub;
    asrc[i] = (const char*)H + ((size_t)offe + row0 + rr)*(F_DIM*2) + skb;
  }
  const char* bsrc[2];
  #pragma unroll
  for (int i=0;i<2;i++){
    int rr = (wid*2+i)*8 + sub;
    bsrc[i] = (const char*)dwt + ((size_t)e*D_DIM + n0 + rr)*(F_DIM*2) + skb;
  }
  f32x4 acc[4][2] = {};
  int wm = wid>>1, wn = wid&1;

  auto STAGE = [&](int buf, int kt){           // 6 gload_lds per thread
    size_t ko = (size_t)kt*BK*2;
    char* base = arena + buf*DN_HALF;
    #pragma unroll
    for (int i=0;i<4;i++) gload16(asrc[i]+ko, base + (wid*4+i)*1024);
    #pragma unroll
    for (int i=0;i<2;i++) gload16(bsrc[i]+ko, base + BM*BK*2 + (wid*2+i)*1024);
  };
  auto COMPUTE = [&](int buf){
    const char* base = arena + buf*DN_HALF;
    const char* Bs = base + BM*BK*2;
    #pragma unroll
    for (int s=0;s<2;s++){
      int kc = s*4 + (lane>>4);
      bf16x8 a[4], bb[2];
      #pragma unroll
      for (int m=0;m<4;m++){
        int ar = wm*64 + m*16 + (lane&15);
        a[m] = *(const bf16x8*)(base + ar*128 + ((kc<<4) ^ ((ar&7)<<4)));
      }
      #pragma unroll
      for (int n=0;n<2;n++){
        int br = wn*32 + n*16 + (lane&15);
        bb[n] = *(const bf16x8*)(Bs + br*128 + ((kc<<4) ^ ((br&7)<<4)));
      }
      #pragma unroll
      for (int m=0;m<4;m++){
        #pragma unroll
        for (int n=0;n<2;n++)
          acc[m][n] = __builtin_amdgcn_mfma_f32_16x16x32_bf16(a[m], bb[n], acc[m][n], 0,0,0);
      }
    }
  };

  STAGE(0, 0);
  STAGE(1, 1);
  #pragma unroll 1
  for (int t=0; t<F_DIM/BK-1; ++t){
    asm volatile("s_waitcnt vmcnt(6)" ::: "memory");
    __builtin_amdgcn_s_barrier();
    __builtin_amdgcn_sched_barrier(0);
    COMPUTE(t & 1);
    __builtin_amdgcn_s_barrier();
    __builtin_amdgcn_sched_barrier(0);
    if (t+2 < F_DIM/BK) STAGE(t & 1, t+2);
  }
  asm volatile("s_waitcnt vmcnt(0)" ::: "memory");
  __builtin_amdgcn_s_barrier();
  __builtin_amdgcn_sched_barrier(0);
  COMPUTE((F_DIM/BK-1) & 1);

  #pragma unroll
  for (int m=0;m<4;m++){
    #pragma unroll
    for (int j=0;j<4;j++){
      int row = wm*64 + m*16 + ((lane>>4)<<2) + j;
      if (row < rem){
        int tok = slot_token[e*CAP + row0 + row];
        #pragma unroll
        for (int n=0;n<2;n++){
          int col = n0 + wn*32 + n*16 + (lane&15);
          atomicAdd(&out[(size_t)tok*D_DIM + col], acc[m][n][j]);
        }
      }
    }
  }
}

extern "C" void kernel_launch(void* const* d_in, const int* in_sizes, int n_in,
                              void* d_out, int out_size, void* d_ws, size_t ws_size,
                              hipStream_t stream){
  const float* x  = (const float*)d_in[0];
  const float* rw = (const float*)d_in[1];
  const float* gw = (const float*)d_in[2];
  const float* uw = (const float*)d_in[3];
  const float* dw = (const float*)d_in[4];
  float* out = (float*)d_out;

  char* w = (char*)d_ws;
  unsigned short* Xg  = (unsigned short*)w;  w += (size_t)E_NUM*CAP*D_DIM*2;
  unsigned short* gwt = (unsigned short*)w;  w += (size_t)E_NUM*D_DIM*F_DIM*2;
  unsigned short* uwt = (unsigned short*)w;  w += (size_t)E_NUM*D_DIM*F_DIM*2;
  unsigned short* dwt = (unsigned short*)w;  w += (size_t)E_NUM*F_DIM*D_DIM*2;
  unsigned short* H   = (unsigned short*)w;  w += (size_t)(T_TOK*2 + BM)*F_DIM*2;
  int*   slot_token = (int*)w;               w += (size_t)E_NUM*CAP*4;
  float* slot_w     = (float*)w;             w += (size_t)E_NUM*CAP*4;
  char* meta = w;
  int*   cnt  = (int*)w;       w += E_NUM*CSTRIDE*4;
  float* Psum = (float*)w;     w += E_NUM*CSTRIDE*4;
  float* zsum = (float*)w;     w += 128;
  size_t meta_bytes = (size_t)(w - meta);

  (void)hipMemsetAsync(d_out, 0, (size_t)out_size*sizeof(float), stream);
  (void)hipMemsetAsync(meta, 0, meta_bytes, stream);

  router_kernel<<<T_TOK/RB_TOK, 256, 0, stream>>>(
      x, rw, Xg, cnt, slot_token, slot_w, Psum, zsum);
  transpose_kernel<<<3*1024, 256, 0, stream>>>(gw, uw, dw, gwt, uwt, dwt);
  gemm_gateup<<<E_NUM*MT*NT_GU, 256, 0, stream>>>(Xg, gwt, uwt, cnt, slot_w, H);
  gemm_down<<<E_NUM*MT*NT_DN, 256, 0, stream>>>(H, dwt, cnt, slot_token, out, Psum, zsum);
}

// Round 12
// 188.139 us; speedup vs baseline: 1.1134x; 1.1134x over previous
//
#include <hip/hip_runtime.h>

#define T_TOK 4096
#define D_DIM 512
#define F_DIM 1024
#define E_NUM 8
#define CAP   2048
#define BM    128
#define BN    64
#define BK    64
#define MT    (CAP/BM)      // 16
#define NT_GU (F_DIM/BN)    // 16
#define NT_DN (D_DIM/BN)    // 8
#define RB_TOK 16
#define CSTRIDE 32
#define RTR_BLOCKS (T_TOK/RB_TOK)   // 256

#define GU_HALF (BM*BK*2 + 2*BN*BK*2)   // 32768 bytes per buffer
#define DN_HALF (BM*BK*2 + BN*BK*2)     // 24576 bytes per buffer

typedef __bf16 bf16x8 __attribute__((ext_vector_type(8)));
typedef float  f32x4  __attribute__((ext_vector_type(4)));

__device__ __forceinline__ unsigned short f2bf(float f){
  unsigned int u = __builtin_bit_cast(unsigned int, f);
  u += 0x7FFFu + ((u >> 16) & 1u);
  return (unsigned short)(u >> 16);
}
__device__ __forceinline__ unsigned pk2(float a, float b){
  return (unsigned)f2bf(a) | ((unsigned)f2bf(b)<<16);
}
__device__ __forceinline__ void gload16(const void* g, void* l){
  __builtin_amdgcn_global_load_lds(
      (const __attribute__((address_space(1))) unsigned int*)g,
      (__attribute__((address_space(3))) unsigned int*)l, 16, 0, 0);
}

// ============ fused prep: router (blocks 0..255, 4 tok/wave) + 3 transposes ============
__global__ __launch_bounds__(256) void prep_kernel(
    const float* __restrict__ x, const float* __restrict__ rw,
    const float* __restrict__ gw, const float* __restrict__ uw, const float* __restrict__ dw,
    unsigned short* __restrict__ Xg,
    unsigned short* __restrict__ gwt, unsigned short* __restrict__ uwt, unsigned short* __restrict__ dwt,
    int* __restrict__ cnt, int* __restrict__ slot_token, float* __restrict__ slot_w,
    float* __restrict__ Psum, float* __restrict__ zsum)
{
  __shared__ __align__(16) char smem[18432];
  int b = blockIdx.x;
  int tid = threadIdx.x;

  if (b >= RTR_BLOCKS){
    // ---- transpose: [E][R][C] fp32 -> [E][C][R] bf16, b32-pack + XOR, conflict-free ----
    unsigned* tw = (unsigned*)smem;   // 8 KB: 64 cols x 32 k-pair words
    int tb = b - RTR_BLOCKS;
    int seg = tb >> 10;               // 0:gw 1:uw 2:dw
    int r1023 = tb & 1023;
    int e = r1023 >> 7;
    int rr = r1023 & 127;
    const float* in; unsigned short* outp; int R, C, nbx;
    if (seg == 0){ in = gw; outp = gwt; R = D_DIM; C = F_DIM; nbx = F_DIM/64; }
    else if (seg == 1){ in = uw; outp = uwt; R = D_DIM; C = F_DIM; nbx = F_DIM/64; }
    else { in = dw; outp = dwt; R = F_DIM; C = D_DIM; nbx = D_DIM/64; }
    int c0 = (rr % nbx)*64, r0 = (rr / nbx)*64;
    const float* src = in + (size_t)e*R*C;
    unsigned short* dst = outp + (size_t)e*R*C;

    int d2 = tid>>3, fcq = tid&7;
    const float* p0 = src + (size_t)(r0 + 2*d2)*C + c0 + fcq*8;
    float4 a0 = *(const float4*)p0;
    float4 a1 = *(const float4*)(p0+4);
    float4 b0 = *(const float4*)(p0+C);
    float4 b1 = *(const float4*)(p0+C+4);
    float al[8] = {a0.x,a0.y,a0.z,a0.w,a1.x,a1.y,a1.z,a1.w};
    float bl[8] = {b0.x,b0.y,b0.z,b0.w,b1.x,b1.y,b1.z,b1.w};
    unsigned xb = ((unsigned)fcq)<<2;
    #pragma unroll
    for (int j=0;j<8;j++){
      int c = fcq*8 + j;
      tw[c*32 + (d2 ^ xb)] = pk2(al[j], bl[j]);
    }
    __syncthreads();
    int c = tid>>2, q = tid&3;
    unsigned xc = ((unsigned)(c>>3))<<2;
    uint4 v0 = *(const uint4*)&tw[c*32 + ((unsigned)(q*8+0) ^ xc)];
    uint4 v1 = *(const uint4*)&tw[c*32 + ((unsigned)(q*8+4) ^ xc)];
    unsigned short* dp = dst + (size_t)(c0+c)*R + r0 + q*16;
    *(uint4*)dp = v0;
    *(uint4*)(dp+8) = v1;
    return;
  }

  // ---- router: 4 waves x 4 tokens; logits + softmax + top2 + aux + scatter ----
  float* rws          = (float*)smem;                       // 16384 B
  float (*lp)[E_NUM]  = (float(*)[E_NUM])(smem+16384);      // 512 B
  float* lw1          = (float*)(smem+16896);
  float* lw2          = (float*)(smem+16960);
  float* llse         = (float*)(smem+17024);
  int*   li1          = (int*)(smem+17088);
  int*   li2          = (int*)(smem+17152);
  int*   lsl1         = (int*)(smem+17216);
  int*   lsl2         = (int*)(smem+17280);

  int wid = tid>>6, lane = tid&63;
  for (int i = tid; i < E_NUM*D_DIM; i += 256) rws[i] = rw[i];
  __syncthreads();

  uint4 pk[4];
  #pragma unroll
  for (int i=0;i<4;i++){
    int widx = wid*4 + i;
    int t = b*RB_TOK + widx;
    const float* xr = x + (size_t)t*D_DIM + lane*8;
    float4 xa = *(const float4*)xr;
    float4 xc = *(const float4*)(xr+4);
    pk[i].x = pk2(xa.x, xa.y);
    pk[i].y = pk2(xa.z, xa.w);
    pk[i].z = pk2(xc.x, xc.y);
    pk[i].w = pk2(xc.z, xc.w);

    float logit[E_NUM];
    #pragma unroll
    for (int e=0;e<E_NUM;e++){
      const float* wr = rws + e*D_DIM + lane*8;
      float4 wa = *(const float4*)wr;
      float4 wb = *(const float4*)(wr+4);
      float s = xa.x*wa.x + xa.y*wa.y + xa.z*wa.z + xa.w*wa.w
              + xc.x*wb.x + xc.y*wb.y + xc.z*wb.z + xc.w*wb.w;
      #pragma unroll
      for (int m=1;m<64;m<<=1) s += __shfl_xor(s, m);
      logit[e] = s;
    }
    float mx = logit[0];
    #pragma unroll
    for (int e=1;e<E_NUM;e++) mx = fmaxf(mx, logit[e]);
    float p[E_NUM]; float s = 0.f;
    #pragma unroll
    for (int e=0;e<E_NUM;e++){ p[e] = __expf(logit[e]-mx); s += p[e]; }
    float inv = 1.f/s;
    #pragma unroll
    for (int e=0;e<E_NUM;e++) p[e] *= inv;
    float lse = mx + __logf(s);
    int i1 = 0;
    #pragma unroll
    for (int e=1;e<E_NUM;e++) if (logit[e] > logit[i1]) i1 = e;
    int i2 = (i1==0) ? 1 : 0;
    #pragma unroll
    for (int e=0;e<E_NUM;e++) if (e != i1 && logit[e] > logit[i2]) i2 = e;
    if (lane == 0){
      float v1 = p[i1], v2 = p[i2];
      float invw = 1.f/(v1+v2);
      li1[widx] = i1; li2[widx] = i2;
      lw1[widx] = v1*invw; lw2[widx] = v2*invw;
      llse[widx] = lse;
      #pragma unroll
      for (int e=0;e<E_NUM;e++) lp[widx][e] = p[e];
    }
  }
  __syncthreads();

  if (tid < E_NUM){
    int e = tid, c = 0;
    #pragma unroll
    for (int j=0;j<RB_TOK;j++) c += (li1[j]==e) + (li2[j]==e);
    int idx = atomicAdd(&cnt[e*CSTRIDE], c);
    int tbase = b*RB_TOK;
    for (int j=0;j<RB_TOK;j++){
      if (li1[j]==e){ slot_token[e*CAP+idx] = tbase+j; slot_w[e*CAP+idx] = lw1[j]; lsl1[j] = e*CAP+idx; idx++; }
      if (li2[j]==e){ slot_token[e*CAP+idx] = tbase+j; slot_w[e*CAP+idx] = lw2[j]; lsl2[j] = e*CAP+idx; idx++; }
    }
    float ps = 0.f;
    #pragma unroll
    for (int j=0;j<RB_TOK;j++) ps += lp[j][e];
    atomicAdd(&Psum[e*CSTRIDE], ps);
  } else if (tid == 64){
    float zs = 0.f;
    #pragma unroll
    for (int j=0;j<RB_TOK;j++){ float l = llse[j]; zs += l*l; }
    atomicAdd(zsum, zs);
  }
  __syncthreads();

  #pragma unroll
  for (int i=0;i<4;i++){
    int widx = wid*4 + i;
    *(uint4*)((char*)Xg + (size_t)lsl1[widx]*(D_DIM*2) + lane*16) = pk[i];
    *(uint4*)((char*)Xg + (size_t)lsl2[widx]*(D_DIM*2) + lane*16) = pk[i];
  }
}

// ---------------- gate+up GEMM: 2-deep pipeline, counted vmcnt ----------------
__global__ __launch_bounds__(256) void gemm_gateup(
    const unsigned short* __restrict__ Xg, const unsigned short* __restrict__ gwt,
    const unsigned short* __restrict__ uwt,
    const int* __restrict__ cnt,
    const float* __restrict__ slot_w, unsigned short* __restrict__ H)
{
  int fid = blockIdx.x;
  int nid = (fid & 7)*(E_NUM*MT*NT_GU/8) + (fid >> 3);
  int e  = nid >> 8;
  int r  = nid & 255;
  int n0 = (r >> 4) * BN;
  int mt = r & 15;
  int c = cnt[e*CSTRIDE];
  int row0 = mt*BM;
  if (row0 >= c) return;
  int rem = c - row0;
  int offe = 0;
  #pragma unroll
  for (int i=0;i<E_NUM;i++) offe += (i < e) ? cnt[i*CSTRIDE] : 0;
  int tid = threadIdx.x, wid = tid>>6, lane = tid&63;
  __shared__ __align__(16) char arena[2*GU_HALF];

  int sub = lane>>3;
  int skb = ((lane&7)<<4) ^ (sub<<4);
  const char* asrc[4];
  #pragma unroll
  for (int i=0;i<4;i++){
    int rr = (wid*4+i)*8 + sub;
    asrc[i] = (const char*)Xg + ((size_t)e*CAP + row0 + rr)*(D_DIM*2) + skb;
  }
  const char* bgsrc[2]; const char* busrc[2];
  #pragma unroll
  for (int i=0;i<2;i++){
    int rr = (wid*2+i)*8 + sub;
    size_t rowb = ((size_t)e*F_DIM + n0 + rr) * (D_DIM*2);
    bgsrc[i] = (const char*)gwt + rowb + skb;
    busrc[i] = (const char*)uwt + rowb + skb;
  }

  f32x4 accg[4][2] = {};
  f32x4 accu[4][2] = {};
  int wm = wid>>1, wn = wid&1;

  auto STAGE = [&](int buf, int kt){           // 8 gload_lds per thread
    size_t ko = (size_t)kt*BK*2;
    char* base = arena + buf*GU_HALF;
    #pragma unroll
    for (int i=0;i<4;i++)
      gload16(asrc[i]+ko, base + (wid*4+i)*1024);
    #pragma unroll
    for (int i=0;i<2;i++){
      gload16(bgsrc[i]+ko, base + BM*BK*2 + (wid*2+i)*1024);
      gload16(busrc[i]+ko, base + BM*BK*2 + BN*BK*2 + (wid*2+i)*1024);
    }
  };
  auto COMPUTE = [&](int buf){
    const char* base = arena + buf*GU_HALF;
    const char* Bg = base + BM*BK*2;
    const char* Bu = base + BM*BK*2 + BN*BK*2;
    #pragma unroll
    for (int s=0;s<2;s++){
      int kc = s*4 + (lane>>4);
      bf16x8 a[4], bg[2], bu[2];
      #pragma unroll
      for (int m=0;m<4;m++){
        int ar = wm*64 + m*16 + (lane&15);
        a[m] = *(const bf16x8*)(base + ar*128 + ((kc<<4) ^ ((ar&7)<<4)));
      }
      #pragma unroll
      for (int n=0;n<2;n++){
        int br = wn*32 + n*16 + (lane&15);
        int bo = br*128 + ((kc<<4) ^ ((br&7)<<4));
        bg[n] = *(const bf16x8*)(Bg + bo);
        bu[n] = *(const bf16x8*)(Bu + bo);
      }
      #pragma unroll
      for (int m=0;m<4;m++){
        #pragma unroll
        for (int n=0;n<2;n++){
          accg[m][n] = __builtin_amdgcn_mfma_f32_16x16x32_bf16(a[m], bg[n], accg[m][n], 0,0,0);
          accu[m][n] = __builtin_amdgcn_mfma_f32_16x16x32_bf16(a[m], bu[n], accu[m][n], 0,0,0);
        }
      }
    }
  };

  STAGE(0, 0);
  STAGE(1, 1);
  #pragma unroll 1
  for (int t=0; t<D_DIM/BK-1; ++t){
    asm volatile("s_waitcnt vmcnt(8)" ::: "memory");
    __builtin_amdgcn_s_barrier();
    __builtin_amdgcn_sched_barrier(0);
    COMPUTE(t & 1);
    __builtin_amdgcn_s_barrier();
    __builtin_amdgcn_sched_barrier(0);
    if (t+2 < D_DIM/BK) STAGE(t & 1, t+2);
  }
  asm volatile("s_waitcnt vmcnt(0)" ::: "memory");
  __builtin_amdgcn_s_barrier();
  __builtin_amdgcn_sched_barrier(0);
  COMPUTE((D_DIM/BK-1) & 1);

  #pragma unroll
  for (int m=0;m<4;m++){
    #pragma unroll
    for (int j=0;j<4;j++){
      int row = wm*64 + m*16 + ((lane>>4)<<2) + j;
      if (row < rem){
        float wgt = slot_w[e*CAP + row0 + row];
        size_t hb = (size_t)(offe + row0 + row)*F_DIM;
        #pragma unroll
        for (int n=0;n<2;n++){
          int col = n0 + wn*32 + n*16 + (lane&15);
          float g = accg[m][n][j];
          float u = accu[m][n][j];
          float h = g * (1.f/(1.f+__expf(-g))) * u * wgt;
          H[hb + col] = f2bf(h);
        }
      }
    }
  }
}

// ---------------- down GEMM: 2-deep pipeline, counted vmcnt, atomic scatter ----------------
__global__ __launch_bounds__(256) void gemm_down(
    const unsigned short* __restrict__ H, const unsigned short* __restrict__ dwt,
    const int* __restrict__ cnt,
    const int* __restrict__ slot_token, float* __restrict__ out,
    const float* __restrict__ Psum, const float* __restrict__ zsum)
{
  int fid = blockIdx.x;
  int tid = threadIdx.x;
  if (fid == 0 && tid == 0){
    float lb = 0.f;
    #pragma unroll
    for (int e=0;e<E_NUM;e++){
      float f = (float)cnt[e*CSTRIDE] / (float)(T_TOK*2);
      float P = Psum[e*CSTRIDE] / (float)T_TOK;
      lb += f*P;
    }
    float z = zsum[0] / (float)T_TOK;
    out[(size_t)T_TOK*D_DIM] = 0.01f * ((float)E_NUM * lb) + 0.001f * z;
  }
  int nid = (fid & 7)*(E_NUM*MT*NT_DN/8) + (fid >> 3);
  int e  = nid >> 7;
  int r  = nid & 127;
  int n0 = (r >> 4) * BN;
  int mt = r & 15;
  int c = cnt[e*CSTRIDE];
  int row0 = mt*BM;
  if (row0 >= c) return;
  int rem = c - row0;
  int offe = 0;
  #pragma unroll
  for (int i=0;i<E_NUM;i++) offe += (i < e) ? cnt[i*CSTRIDE] : 0;
  int wid = tid>>6, lane = tid&63;
  __shared__ __align__(16) char arena[2*DN_HALF];
  int sub = lane>>3;
  int skb = ((lane&7)<<4) ^ (sub<<4);
  const char* asrc[4];
  #pragma unroll
  for (int i=0;i<4;i++){
    int rr = (wid*4+i)*8 + sub;
    asrc[i] = (const char*)H + ((size_t)offe + row0 + rr)*(F_DIM*2) + skb;
  }
  const char* bsrc[2];
  #pragma unroll
  for (int i=0;i<2;i++){
    int rr = (wid*2+i)*8 + sub;
    bsrc[i] = (const char*)dwt + ((size_t)e*D_DIM + n0 + rr)*(F_DIM*2) + skb;
  }
  f32x4 acc[4][2] = {};
  int wm = wid>>1, wn = wid&1;

  auto STAGE = [&](int buf, int kt){           // 6 gload_lds per thread
    size_t ko = (size_t)kt*BK*2;
    char* base = arena + buf*DN_HALF;
    #pragma unroll
    for (int i=0;i<4;i++) gload16(asrc[i]+ko, base + (wid*4+i)*1024);
    #pragma unroll
    for (int i=0;i<2;i++) gload16(bsrc[i]+ko, base + BM*BK*2 + (wid*2+i)*1024);
  };
  auto COMPUTE = [&](int buf){
    const char* base = arena + buf*DN_HALF;
    const char* Bs = base + BM*BK*2;
    #pragma unroll
    for (int s=0;s<2;s++){
      int kc = s*4 + (lane>>4);
      bf16x8 a[4], bb[2];
      #pragma unroll
      for (int m=0;m<4;m++){
        int ar = wm*64 + m*16 + (lane&15);
        a[m] = *(const bf16x8*)(base + ar*128 + ((kc<<4) ^ ((ar&7)<<4)));
      }
      #pragma unroll
      for (int n=0;n<2;n++){
        int br = wn*32 + n*16 + (lane&15);
        bb[n] = *(const bf16x8*)(Bs + br*128 + ((kc<<4) ^ ((br&7)<<4)));
      }
      #pragma unroll
      for (int m=0;m<4;m++){
        #pragma unroll
        for (int n=0;n<2;n++)
          acc[m][n] = __builtin_amdgcn_mfma_f32_16x16x32_bf16(a[m], bb[n], acc[m][n], 0,0,0);
      }
    }
  };

  STAGE(0, 0);
  STAGE(1, 1);
  #pragma unroll 1
  for (int t=0; t<F_DIM/BK-1; ++t){
    asm volatile("s_waitcnt vmcnt(6)" ::: "memory");
    __builtin_amdgcn_s_barrier();
    __builtin_amdgcn_sched_barrier(0);
    COMPUTE(t & 1);
    __builtin_amdgcn_s_barrier();
    __builtin_amdgcn_sched_barrier(0);
    if (t+2 < F_DIM/BK) STAGE(t & 1, t+2);
  }
  asm volatile("s_waitcnt vmcnt(0)" ::: "memory");
  __builtin_amdgcn_s_barrier();
  __builtin_amdgcn_sched_barrier(0);
  COMPUTE((F_DIM/BK-1) & 1);

  #pragma unroll
  for (int m=0;m<4;m++){
    #pragma unroll
    for (int j=0;j<4;j++){
      int row = wm*64 + m*16 + ((lane>>4)<<2) + j;
      if (row < rem){
        int tok = slot_token[e*CAP + row0 + row];
        #pragma unroll
        for (int n=0;n<2;n++){
          int col = n0 + wn*32 + n*16 + (lane&15);
          atomicAdd(&out[(size_t)tok*D_DIM + col], acc[m][n][j]);
        }
      }
    }
  }
}

extern "C" void kernel_launch(void* const* d_in, const int* in_sizes, int n_in,
                              void* d_out, int out_size, void* d_ws, size_t ws_size,
                              hipStream_t stream){
  const float* x  = (const float*)d_in[0];
  const float* rw = (const float*)d_in[1];
  const float* gw = (const float*)d_in[2];
  const float* uw = (const float*)d_in[3];
  const float* dw = (const float*)d_in[4];
  float* out = (float*)d_out;

  char* w = (char*)d_ws;
  unsigned short* Xg  = (unsigned short*)w;  w += (size_t)E_NUM*CAP*D_DIM*2;
  unsigned short* gwt = (unsigned short*)w;  w += (size_t)E_NUM*D_DIM*F_DIM*2;
  unsigned short* uwt = (unsigned short*)w;  w += (size_t)E_NUM*D_DIM*F_DIM*2;
  unsigned short* dwt = (unsigned short*)w;  w += (size_t)E_NUM*F_DIM*D_DIM*2;
  unsigned short* H   = (unsigned short*)w;  w += (size_t)(T_TOK*2 + BM)*F_DIM*2;
  int*   slot_token = (int*)w;               w += (size_t)E_NUM*CAP*4;
  float* slot_w     = (float*)w;             w += (size_t)E_NUM*CAP*4;
  char* meta = w;
  int*   cnt  = (int*)w;       w += E_NUM*CSTRIDE*4;
  float* Psum = (float*)w;     w += E_NUM*CSTRIDE*4;
  float* zsum = (float*)w;     w += 128;
  size_t meta_bytes = (size_t)(w - meta);

  (void)hipMemsetAsync(d_out, 0, (size_t)out_size*sizeof(float), stream);
  (void)hipMemsetAsync(meta, 0, meta_bytes, stream);

  prep_kernel<<<RTR_BLOCKS + 3*1024, 256, 0, stream>>>(
      x, rw, gw, uw, dw, Xg, gwt, uwt, dwt, cnt, slot_token, slot_w, Psum, zsum);
  gemm_gateup<<<E_NUM*MT*NT_GU, 256, 0, stream>>>(Xg, gwt, uwt, cnt, slot_w, H);
  gemm_down<<<E_NUM*MT*NT_DN, 256, 0, stream>>>(H, dwt, cnt, slot_token, out, Psum, zsum);
}